// Round 1
// baseline (779.031 us; speedup 1.0000x reference)
//
#include <hip/hip_runtime.h>

#define T_LEN 2048
#define BSZ   256
#define NOBS  10

// output offsets (floats)
#define OFF_XR   0
#define OFF_QMU  5242880
#define OFF_QCOV 7340032
#define OFF_PMU  15728640
#define OFF_PCOV 17825792

// workspace offsets (floats)
#define WS_K10   0
#define WS_PP10  20480
#define WS_L10   40960
#define WS_S4    61440
#define WS_TCONV 69632

__device__ __forceinline__ unsigned rotl32(unsigned v, int d) {
  return (v << d) | (v >> (32 - d));
}

// JAX threefry2x32: 20 rounds, key schedule every 4 rounds.
__device__ __forceinline__ void tf_block(unsigned k0, unsigned k1,
                                         unsigned& x0, unsigned& x1) {
  unsigned k2 = k0 ^ k1 ^ 0x1BD11BDAu;
  x0 += k0; x1 += k1;
#define TFR(r) { x0 += x1; x1 = rotl32(x1, r); x1 ^= x0; }
  TFR(13) TFR(15) TFR(26) TFR(6)
  x0 += k1; x1 += k2 + 1u;
  TFR(17) TFR(29) TFR(16) TFR(24)
  x0 += k2; x1 += k0 + 2u;
  TFR(13) TFR(15) TFR(26) TFR(6)
  x0 += k0; x1 += k1 + 3u;
  TFR(17) TFR(29) TFR(16) TFR(24)
  x0 += k1; x1 += k2 + 4u;
  TFR(13) TFR(15) TFR(26) TFR(6)
  x0 += k2; x1 += k0 + 5u;
#undef TFR
}

// XLA ErfInv32 (Giles polynomial), matches lax.erf_inv f32 lowering.
__device__ __forceinline__ float erfinv_xla(float x) {
  float w = -log1pf(-x * x);
  float p;
  if (w < 5.0f) {
    w = w - 2.5f;
    p = 2.81022636e-08f;
    p = fmaf(p, w, 3.43273939e-07f);
    p = fmaf(p, w, -3.5233877e-06f);
    p = fmaf(p, w, -4.39150654e-06f);
    p = fmaf(p, w, 0.00021858087f);
    p = fmaf(p, w, -0.00125372503f);
    p = fmaf(p, w, -0.00417768164f);
    p = fmaf(p, w, 0.246640727f);
    p = fmaf(p, w, 1.50140941f);
  } else {
    w = sqrtf(w) - 3.0f;
    p = -0.000200214257f;
    p = fmaf(p, w, 0.000100950558f);
    p = fmaf(p, w, 0.00134934322f);
    p = fmaf(p, w, -0.00367342844f);
    p = fmaf(p, w, 0.00573950773f);
    p = fmaf(p, w, -0.0076224613f);
    p = fmaf(p, w, 0.00943887047f);
    p = fmaf(p, w, 1.00167406f);
    p = fmaf(p, w, 2.83297682f);
  }
  return p * x;
}

// K1: block 0 = serial batch-independent Riccati chain (with bit-convergence
// cutoff); blocks 1..2048 = encoder z_mu, stored t-major into q_cov region.
__global__ void __launch_bounds__(256) svae_k1(
    const float* __restrict__ x,
    const float* __restrict__ ew1, const float* __restrict__ eb1,
    const float* __restrict__ ewx, const float* __restrict__ ebx,
    const float* __restrict__ A, const float* __restrict__ Q,
    float* __restrict__ zmu, float* __restrict__ wsf) {
  if (blockIdx.x == 0) {
    if (threadIdx.x != 0) return;
    float Am[16], Qm[16];
#pragma unroll
    for (int i = 0; i < 16; ++i) Am[i] = A[i];
#pragma unroll
    for (int i = 0; i < 4; ++i)
#pragma unroll
      for (int j = 0; j < 4; ++j) {
        float s = 0.f;
#pragma unroll
        for (int k = 0; k < 4; ++k) s += Q[k*4+i] * Q[k*4+j];
        Qm[i*4+j] = s;
      }
    float P[16] = {1,0,0,0, 0,1,0,0, 0,0,1,0, 0,0,0,1};
    unsigned pb1[10], pb2[10];
#pragma unroll
    for (int i = 0; i < 10; ++i) { pb1[i] = 0xDEADBEEFu; pb2[i] = 0xFEEDFACEu; }
    int tc = T_LEN - 1;
    float* K10  = wsf + WS_K10;
    float* Pp10 = wsf + WS_PP10;
    float* L10  = wsf + WS_L10;
    for (int t = 0; t < T_LEN; ++t) {
      float M[16];
#pragma unroll
      for (int i = 0; i < 4; ++i)
#pragma unroll
        for (int l = 0; l < 4; ++l) {
          float s = Am[i*4+0]*P[0*4+l];
          s += Am[i*4+1]*P[1*4+l];
          s += Am[i*4+2]*P[2*4+l];
          s += Am[i*4+3]*P[3*4+l];
          M[i*4+l] = s;
        }
      float Pp[16];
#pragma unroll
      for (int i = 0; i < 4; ++i)
#pragma unroll
        for (int j = 0; j < 4; ++j) {
          if (j > i) continue;
          float s = Qm[i*4+j];
          s += M[i*4+0]*Am[j*4+0];
          s += M[i*4+1]*Am[j*4+1];
          s += M[i*4+2]*Am[j*4+2];
          s += M[i*4+3]*Am[j*4+3];
          Pp[i*4+j] = s; Pp[j*4+i] = s;
        }
      // chol(S = Pp + I)
      float l00 = sqrtf(Pp[0]+1.f); float i00 = 1.f/l00;
      float l10 = Pp[4]*i00, l20 = Pp[8]*i00, l30 = Pp[12]*i00;
      float l11 = sqrtf(Pp[5]+1.f - l10*l10); float i11 = 1.f/l11;
      float l21 = (Pp[9]  - l20*l10)*i11;
      float l31 = (Pp[13] - l30*l10)*i11;
      float l22 = sqrtf(Pp[10]+1.f - l20*l20 - l21*l21); float i22 = 1.f/l22;
      float l32 = (Pp[14] - l30*l20 - l31*l21)*i22;
      float l33 = sqrtf(Pp[15]+1.f - l30*l30 - l31*l31 - l32*l32); float i33 = 1.f/l33;
      // L^{-1}
      float Li10 = -(l10*i00)*i11;
      float Li20 = -(l20*i00 + l21*Li10)*i22;
      float Li21 = -(l21*i11)*i22;
      float Li30 = -(l30*i00 + l31*Li10 + l32*Li20)*i33;
      float Li31 = -(l31*i11 + l32*Li21)*i33;
      float Li32 = -(l32*i22)*i33;
      // Sinv = L^{-T} L^{-1}
      float Si00 = i00*i00 + Li10*Li10 + Li20*Li20 + Li30*Li30;
      float Si10 = Li10*i11 + Li20*Li21 + Li30*Li31;
      float Si11 = i11*i11 + Li21*Li21 + Li31*Li31;
      float Si20 = Li20*i22 + Li30*Li32;
      float Si21 = Li21*i22 + Li31*Li32;
      float Si22 = i22*i22 + Li32*Li32;
      float Si30 = Li30*i33;
      float Si31 = Li31*i33;
      float Si32 = Li32*i33;
      float Si33 = i33*i33;
      // K = I - Sinv (= posterior P since H=R=I)
      float Kv[10];
      Kv[0] = 1.f - Si00; Kv[1] = -Si10; Kv[2] = 1.f - Si11;
      Kv[3] = -Si20; Kv[4] = -Si21; Kv[5] = 1.f - Si22;
      Kv[6] = -Si30; Kv[7] = -Si31; Kv[8] = -Si32; Kv[9] = 1.f - Si33;
      // chol(K + 1e-3 I) for the sampling path
      float c00 = sqrtf(Kv[0]+1e-3f); float j00 = 1.f/c00;
      float c10 = Kv[1]*j00, c20 = Kv[3]*j00, c30 = Kv[6]*j00;
      float c11 = sqrtf(Kv[2]+1e-3f - c10*c10); float j11 = 1.f/c11;
      float c21 = (Kv[4] - c20*c10)*j11;
      float c31 = (Kv[7] - c30*c10)*j11;
      float c22 = sqrtf(Kv[5]+1e-3f - c20*c20 - c21*c21); float j22 = 1.f/c22;
      float c32 = (Kv[8] - c30*c20 - c31*c21)*j22;
      float c33 = sqrtf(Kv[9]+1e-3f - c30*c30 - c31*c31 - c32*c32);
      {
        float* kw = K10 + t*10;
#pragma unroll
        for (int i = 0; i < 10; ++i) kw[i] = Kv[i];
        float* pw = Pp10 + t*10;
        pw[0]=Pp[0]; pw[1]=Pp[4]; pw[2]=Pp[5]; pw[3]=Pp[8]; pw[4]=Pp[9];
        pw[5]=Pp[10]; pw[6]=Pp[12]; pw[7]=Pp[13]; pw[8]=Pp[14]; pw[9]=Pp[15];
        float* lw = L10 + t*10;
        lw[0]=c00; lw[1]=c10; lw[2]=c11; lw[3]=c20; lw[4]=c21;
        lw[5]=c22; lw[6]=c30; lw[7]=c31; lw[8]=c32; lw[9]=c33;
      }
      unsigned nb[10];
#pragma unroll
      for (int i = 0; i < 10; ++i) nb[i] = __float_as_uint(Kv[i]);
      bool eq1 = true, eq2 = true;
#pragma unroll
      for (int i = 0; i < 10; ++i) { eq1 &= (nb[i]==pb1[i]); eq2 &= (nb[i]==pb2[i]); }
      if (eq1 || eq2) { tc = t; break; }
#pragma unroll
      for (int i = 0; i < 10; ++i) { pb2[i] = pb1[i]; pb1[i] = nb[i]; }
      P[0]=Kv[0];  P[1]=Kv[1];  P[2]=Kv[3];  P[3]=Kv[6];
      P[4]=Kv[1];  P[5]=Kv[2];  P[6]=Kv[4];  P[7]=Kv[7];
      P[8]=Kv[3];  P[9]=Kv[4];  P[10]=Kv[5]; P[11]=Kv[8];
      P[12]=Kv[6]; P[13]=Kv[7]; P[14]=Kv[8]; P[15]=Kv[9];
    }
    *((int*)(wsf + WS_TCONV)) = tc;
    return;
  }
  // encoder: block = one t, 256 b's
  int t = blockIdx.x - 1;
  int b = threadIdx.x;
  const float* xp = x + ((size_t)b * T_LEN + t) * NOBS;
  float xv[10];
#pragma unroll
  for (int i = 0; i < 10; ++i) xv[i] = xp[i];
  float h[6];
#pragma unroll
  for (int k = 0; k < 6; ++k) {
    float s = eb1[k];
#pragma unroll
    for (int i = 0; i < 10; ++i) s += xv[i]*ew1[i*6+k];
    h[k] = fmaxf(s, 0.f);
  }
  float z[4];
#pragma unroll
  for (int j = 0; j < 4; ++j) {
    float s = ebx[j];
#pragma unroll
    for (int k = 0; k < 6; ++k) s += h[k]*ewx[k*4+j];
    z[j] = s;
  }
  *reinterpret_cast<float4*>(zmu + (size_t)(t*BSZ + b)*4) =
      make_float4(z[0], z[1], z[2], z[3]);
}

// K2: block 0 = serial PRNG key chain (JAX partitionable mode) + parallel
// u-gen + s_t = u^T L; block 1 = 256 per-batch mu recursions.
__global__ void __launch_bounds__(256) svae_k2(
    const float* __restrict__ A, const float* __restrict__ bvec,
    const int* __restrict__ seedp,
    const float* __restrict__ wsc,
    const float* __restrict__ zmu,
    float* __restrict__ wsf,
    float* __restrict__ q_mu, float* __restrict__ p_mu) {
  __shared__ unsigned keys[2 * T_LEN];
  if (blockIdx.x == 0) {
    if (threadIdx.x == 0) {
      long long sd = (long long)(*seedp);
      unsigned long long us = (unsigned long long)sd;
      unsigned k0 = (unsigned)(us >> 32), k1 = (unsigned)(us & 0xFFFFFFFFull);
      for (int t = 0; t < T_LEN; ++t) {
        keys[2*t] = k0; keys[2*t+1] = k1;
        unsigned x0 = 0u, x1 = 0u;          // split fold-like: ctr (0,0)
        tf_block(k0, k1, x0, x1);
        k0 = x0; k1 = x1;
      }
    }
    __syncthreads();
    const float* L10 = wsc + WS_L10;
    int tc = *((const int*)(wsc + WS_TCONV));
    const float LO = __uint_as_float(0xBF7FFFFFu);   // nextafter(-1,0)
    float* s4 = wsf + WS_S4;
    for (int t = threadIdx.x; t < T_LEN; t += 256) {
      unsigned K0 = keys[2*t], K1 = keys[2*t+1];
      unsigned s0 = 0u, s1 = 1u;            // skey: ctr (0,1)
      tf_block(K0, K1, s0, s1);
      float n[4];
#pragma unroll
      for (int i = 0; i < 4; ++i) {
        unsigned y0 = 0u, y1 = (unsigned)i;  // bits: ctr (0,i), fold xor
        tf_block(s0, s1, y0, y1);
        unsigned bits = y0 ^ y1;
        float f = __uint_as_float((bits >> 9) | 0x3F800000u) - 1.0f;
        float v = fmaxf(LO, f * 2.0f + LO);
        n[i] = 1.41421356237309505f * erfinv_xla(v);
      }
      const float* Lp = L10 + (size_t)((t < tc) ? t : tc) * 10;
      float s_0 = n[0]*Lp[0] + n[1]*Lp[1] + n[2]*Lp[3] + n[3]*Lp[6];
      float s_1 = n[1]*Lp[2] + n[2]*Lp[4] + n[3]*Lp[7];
      float s_2 = n[2]*Lp[5] + n[3]*Lp[8];
      float s_3 = n[3]*Lp[9];
      *reinterpret_cast<float4*>(s4 + 4*t) = make_float4(s_0, s_1, s_2, s_3);
    }
    return;
  }
  // mu recursion: thread = batch element
  int b = threadIdx.x;
  const float* K10 = wsc + WS_K10;
  int tc = *((const int*)(wsc + WS_TCONV));
  float Am[16];
#pragma unroll
  for (int i = 0; i < 16; ++i) Am[i] = A[i];
  float b0 = bvec[0], b1 = bvec[1], b2 = bvec[2], b3 = bvec[3];
  float mu0 = 0.f, mu1 = 0.f, mu2 = 0.f, mu3 = 0.f;
  float4 zc = *reinterpret_cast<const float4*>(zmu + (size_t)(0*BSZ + b)*4);
  float4 zn = *reinterpret_cast<const float4*>(zmu + (size_t)(1*BSZ + b)*4);
  float kc[10], kn[10];
#pragma unroll
  for (int i = 0; i < 10; ++i) kc[i] = K10[i];
  {
    const float* kp = K10 + (size_t)((1 < tc) ? 1 : tc) * 10;
#pragma unroll
    for (int i = 0; i < 10; ++i) kn[i] = kp[i];
  }
  for (int t = 0; t < T_LEN; ++t) {
    float4 zf = zc; float kf[10];
    if (t + 2 < T_LEN) {
      zf = *reinterpret_cast<const float4*>(zmu + (size_t)((t+2)*BSZ + b)*4);
      const float* kp = K10 + (size_t)((t+2 < tc) ? t+2 : tc) * 10;
#pragma unroll
      for (int i = 0; i < 10; ++i) kf[i] = kp[i];
    } else {
#pragma unroll
      for (int i = 0; i < 10; ++i) kf[i] = kn[i];
    }
    float mp0 = b0 + mu0*Am[0] + mu1*Am[4] + mu2*Am[8]  + mu3*Am[12];
    float mp1 = b1 + mu0*Am[1] + mu1*Am[5] + mu2*Am[9]  + mu3*Am[13];
    float mp2 = b2 + mu0*Am[2] + mu1*Am[6] + mu2*Am[10] + mu3*Am[14];
    float mp3 = b3 + mu0*Am[3] + mu1*Am[7] + mu2*Am[11] + mu3*Am[15];
    float r0 = zc.x - mp0, r1 = zc.y - mp1, r2 = zc.z - mp2, r3 = zc.w - mp3;
    mu0 = mp0 + kc[0]*r0 + kc[1]*r1 + kc[3]*r2 + kc[6]*r3;
    mu1 = mp1 + kc[1]*r0 + kc[2]*r1 + kc[4]*r2 + kc[7]*r3;
    mu2 = mp2 + kc[3]*r0 + kc[4]*r1 + kc[5]*r2 + kc[8]*r3;
    mu3 = mp3 + kc[6]*r0 + kc[7]*r1 + kc[8]*r2 + kc[9]*r3;
    *reinterpret_cast<float4*>(p_mu + (size_t)(t*BSZ + b)*4) =
        make_float4(mp0, mp1, mp2, mp3);
    *reinterpret_cast<float4*>(q_mu + (size_t)(t*BSZ + b)*4) =
        make_float4(mu0, mu1, mu2, mu3);
    zc = zn; zn = zf;
#pragma unroll
    for (int i = 0; i < 10; ++i) { kc[i] = kn[i]; kn[i] = kf[i]; }
  }
}

// K3: blocks [0,2048) = zhat + decoder -> x_recon; [2048,4096) = cov broadcast.
__global__ void __launch_bounds__(256) svae_k3(
    const float* __restrict__ q_mu, const float* __restrict__ wsc,
    const float* __restrict__ dw1, const float* __restrict__ db1,
    const float* __restrict__ dw2, const float* __restrict__ db2,
    float* __restrict__ xr, float* __restrict__ q_cov, float* __restrict__ p_cov) {
  int blk = blockIdx.x;
  int b = threadIdx.x;
  if (blk < T_LEN) {
    int t = blk;
    const float* s4 = wsc + WS_S4;
    float4 mu = *reinterpret_cast<const float4*>(q_mu + (size_t)(t*BSZ + b)*4);
    float4 sv = *reinterpret_cast<const float4*>(s4 + 4*t);
    float z0 = mu.x + sv.x, z1 = mu.y + sv.y, z2 = mu.z + sv.z, z3 = mu.w + sv.w;
    float hd[6];
#pragma unroll
    for (int k = 0; k < 6; ++k) {
      float v = db1[k] + z0*dw1[k] + z1*dw1[6+k] + z2*dw1[12+k] + z3*dw1[18+k];
      hd[k] = fmaxf(v, 0.f);
    }
    float* xo = xr + ((size_t)b * T_LEN + t) * 10;
#pragma unroll
    for (int o = 0; o < 10; ++o) {
      float v = db2[o];
#pragma unroll
      for (int k = 0; k < 6; ++k) v += hd[k]*dw2[k*10+o];
      xo[o] = v;
    }
  } else {
    int t = blk - T_LEN;
    int tc = *((const int*)(wsc + WS_TCONV));
    int tt = (t < tc) ? t : tc;
    const float* kp = wsc + WS_K10 + (size_t)tt*10;
    const float* pp = wsc + WS_PP10 + (size_t)tt*10;
    float kv[10], pv[10];
#pragma unroll
    for (int i = 0; i < 10; ++i) { kv[i] = kp[i]; pv[i] = pp[i]; }
    float* qc = q_cov + (size_t)(t*BSZ + b)*16;
    float* pc = p_cov + (size_t)(t*BSZ + b)*16;
    const int mp[16] = {0,1,3,6, 1,2,4,7, 3,4,5,8, 6,7,8,9};
#pragma unroll
    for (int r = 0; r < 4; ++r) {
      *reinterpret_cast<float4*>(qc + r*4) = make_float4(
          kv[mp[r*4]], kv[mp[r*4+1]], kv[mp[r*4+2]], kv[mp[r*4+3]]);
      *reinterpret_cast<float4*>(pc + r*4) = make_float4(
          pv[mp[r*4]], pv[mp[r*4+1]], pv[mp[r*4+2]], pv[mp[r*4+3]]);
    }
  }
}

extern "C" void kernel_launch(void* const* d_in, const int* in_sizes, int n_in,
                              void* d_out, int out_size, void* d_ws, size_t ws_size,
                              hipStream_t stream) {
  const float* x   = (const float*)d_in[0];
  const float* ew1 = (const float*)d_in[1];
  const float* eb1 = (const float*)d_in[2];
  const float* ewx = (const float*)d_in[3];
  const float* ebx = (const float*)d_in[4];
  // d_in[5], d_in[6]: enc_wl/enc_bl -- unused by the filter
  const float* dw1 = (const float*)d_in[7];
  const float* db1 = (const float*)d_in[8];
  const float* dw2 = (const float*)d_in[9];
  const float* db2 = (const float*)d_in[10];
  const float* Ain = (const float*)d_in[11];
  const float* bin = (const float*)d_in[12];
  const float* Qin = (const float*)d_in[13];
  const int* seed  = (const int*)d_in[14];

  float* out   = (float*)d_out;
  float* xr    = out + OFF_XR;
  float* q_mu  = out + OFF_QMU;
  float* q_cov = out + OFF_QCOV;
  float* p_mu  = out + OFF_PMU;
  float* p_cov = out + OFF_PCOV;
  float* zmu   = q_cov;            // scratch in q_cov region (overwritten by K3)
  float* wsf   = (float*)d_ws;

  svae_k1<<<T_LEN + 1, 256, 0, stream>>>(x, ew1, eb1, ewx, ebx, Ain, Qin,
                                         zmu, wsf);
  svae_k2<<<2, 256, 0, stream>>>(Ain, bin, seed, wsf, zmu, wsf, q_mu, p_mu);
  svae_k3<<<2 * T_LEN, 256, 0, stream>>>(q_mu, wsf, dw1, db1, dw2, db2,
                                         xr, q_cov, p_cov);
}